// Round 11
// baseline (356.400 us; speedup 1.0000x reference)
//
#include <hip/hip_runtime.h>

// ---------- types ----------
typedef __bf16 bf16x8 __attribute__((ext_vector_type(8)));
typedef __bf16 bf16x4 __attribute__((ext_vector_type(4)));
typedef float  f32x4  __attribute__((ext_vector_type(4)));

// async global->LDS, 16B per lane; LDS dest = wave-uniform base + lane*16
__device__ __forceinline__ void cp16(void* lds, const void* g) {
  __builtin_amdgcn_global_load_lds(
      (const __attribute__((address_space(1))) unsigned int*)g,
      (__attribute__((address_space(3))) unsigned int*)lds, 16, 0, 0);
}

#define VMCNT0  asm volatile("s_waitcnt vmcnt(0)" ::: "memory")
#define LGKM0   asm volatile("s_waitcnt lgkmcnt(0)" ::: "memory")
#define BARRAW  __builtin_amdgcn_s_barrier
#define MFMA    __builtin_amdgcn_mfma_f32_16x16x32_bf16

// =====================================================================
// ALGORITHM (r5 restructure): K/V never materialized.
//   scores = (Q@Wk) . E ; F_unnorm = P @ E (fused, E read once)
//   Fout = L2norm((F_unnorm@Wv^T)@Wo^T)  (rowsum cancels in L2 norm)
// r11: (1) fused_main v5 -- Er deleted; GEMM1 B-frags read DIRECTLY
// from global row-major E (L2-hot, same lines EtT staging fetched).
// LDS 77->44 KB -> 3 blocks/CU = 12 waves (r10 lesson: 2 blocks x 4
// waves = same 8 waves as r9; waves/CU is the BW lever to test).
// (2) final_kernel v4 -- 2 rows/block halves the L2 weight re-read
// (r8's 2-row failure was its shuffle chain, kept out).
// Fixed harness cost in dur: ~155us of 512MiB poison-fills.
// =====================================================================

// =====================================================================
// cvt_small: Wq->Wqb bf16, T->Tbf bf16, Wk->WkT bf16 [512m][256d],
//            Wv->WvT f32 [512m][256d], Wo->WoT f32 [256d][512m]
// =====================================================================
__global__ __launch_bounds__(256) void cvt_small(const float* __restrict__ Wq,
                                                 const float* __restrict__ Wk,
                                                 const float* __restrict__ Wv,
                                                 const float* __restrict__ Wo,
                                                 const float* __restrict__ T,
                                                 __bf16* __restrict__ Wqb,
                                                 __bf16* __restrict__ Tbf,
                                                 __bf16* __restrict__ WkT,
                                                 float* __restrict__ WvT,
                                                 float* __restrict__ WoT) {
  const int idx = blockIdx.x * 256 + threadIdx.x;
  if (idx < 32768) {
    const int o = idx * 4;
    f32x4 v = *(const f32x4*)(Wq + o);
    bf16x4 b;
    b[0] = (__bf16)v[0]; b[1] = (__bf16)v[1];
    b[2] = (__bf16)v[2]; b[3] = (__bf16)v[3];
    *(bf16x4*)(Wqb + o) = b;
  } else if (idx < 98304) {
    const int o = (idx - 32768) * 4;
    f32x4 v = *(const f32x4*)(T + o);
    bf16x4 b;
    b[0] = (__bf16)v[0]; b[1] = (__bf16)v[1];
    b[2] = (__bf16)v[2]; b[3] = (__bf16)v[3];
    *(bf16x4*)(Tbf + o) = b;
  } else if (idx < 106496) {
    const int t2 = idx - 98304;                 // Wk [256 d][512 m] -> WkT
    const int d0 = (t2 >> 7) * 4, m0 = (t2 & 127) * 4;
    f32x4 r0 = *(const f32x4*)(Wk + (size_t)(d0 + 0) * 512 + m0);
    f32x4 r1 = *(const f32x4*)(Wk + (size_t)(d0 + 1) * 512 + m0);
    f32x4 r2 = *(const f32x4*)(Wk + (size_t)(d0 + 2) * 512 + m0);
    f32x4 r3 = *(const f32x4*)(Wk + (size_t)(d0 + 3) * 512 + m0);
#pragma unroll
    for (int j = 0; j < 4; ++j) {
      bf16x4 o;
      o[0] = (__bf16)r0[j]; o[1] = (__bf16)r1[j];
      o[2] = (__bf16)r2[j]; o[3] = (__bf16)r3[j];
      *(bf16x4*)(WkT + (size_t)(m0 + j) * 256 + d0) = o;
    }
  } else if (idx < 114688) {
    const int t2 = idx - 106496;                // Wv [256 d][512 m] -> WvT f32
    const int d0 = (t2 >> 7) * 4, m0 = (t2 & 127) * 4;
    f32x4 r0 = *(const f32x4*)(Wv + (size_t)(d0 + 0) * 512 + m0);
    f32x4 r1 = *(const f32x4*)(Wv + (size_t)(d0 + 1) * 512 + m0);
    f32x4 r2 = *(const f32x4*)(Wv + (size_t)(d0 + 2) * 512 + m0);
    f32x4 r3 = *(const f32x4*)(Wv + (size_t)(d0 + 3) * 512 + m0);
#pragma unroll
    for (int j = 0; j < 4; ++j) {
      f32x4 o;
      o[0] = r0[j]; o[1] = r1[j]; o[2] = r2[j]; o[3] = r3[j];
      *(f32x4*)(WvT + (size_t)(m0 + j) * 256 + d0) = o;
    }
  } else {
    const int t2 = idx - 114688;                // Wo [512 m][256 d] -> WoT f32
    const int m0 = (t2 >> 6) * 4, d0 = (t2 & 63) * 4;
    f32x4 r0 = *(const f32x4*)(Wo + (size_t)(m0 + 0) * 256 + d0);
    f32x4 r1 = *(const f32x4*)(Wo + (size_t)(m0 + 1) * 256 + d0);
    f32x4 r2 = *(const f32x4*)(Wo + (size_t)(m0 + 2) * 256 + d0);
    f32x4 r3 = *(const f32x4*)(Wo + (size_t)(m0 + 3) * 256 + d0);
#pragma unroll
    for (int j = 0; j < 4; ++j) {
      f32x4 o;
      o[0] = r0[j]; o[1] = r1[j]; o[2] = r2[j]; o[3] = r3[j];
      *(f32x4*)(WoT + (size_t)(d0 + j) * 512 + m0) = o;
    }
  }
}

// =====================================================================
// qproj: Qw[bk][d] = T@Wq^T (verbatim proven m97 path, grid 8)
// =====================================================================
__global__ __launch_bounds__(256) void qproj(const __bf16* __restrict__ Wqb,
                                             const __bf16* __restrict__ Tbf,
                                             __bf16* __restrict__ Qw) {
  __shared__ __align__(16) __bf16 At[4096];
  __shared__ __align__(16) __bf16 Bt[4096];
  const int tid = threadIdx.x, lane = tid & 63;
  const int q = lane >> 4, ln = lane & 15;
  const int w = tid >> 6, wm = w >> 1, wn = w & 1;
  const int t = blockIdx.x;
  const int nbase = (t & 3) * 128;   // T rows (bk)
  const int mbase = (t >> 2) * 128;  // Wq rows (d)
  f32x4 acc[4][4] = {};
  for (int kt = 0; kt < 16; ++kt) {
    const int k0 = kt * 32;
    __syncthreads();
#pragma unroll
    for (int s = 0; s < 2; ++s) {
      const int cbase = (tid & 192) + s * 256;
      const int cc = cbase + lane;
      const int row = cc >> 2, kc = (cc & 3) * 8;
      cp16(&At[cbase * 8], Wqb + (size_t)(mbase + row) * 512 + k0 + kc);
      cp16(&Bt[cbase * 8], Tbf + (size_t)(nbase + row) * 512 + k0 + kc);
    }
    __syncthreads();
    bf16x8 af[4], bfr[4];
#pragma unroll
    for (int f = 0; f < 4; ++f) {
      af[f]  = *(const bf16x8*)&At[(wm * 64 + f * 16 + ln) * 32 + q * 8];
      bfr[f] = *(const bf16x8*)&Bt[(wn * 64 + f * 16 + ln) * 32 + q * 8];
    }
#pragma unroll
    for (int fm = 0; fm < 4; ++fm)
#pragma unroll
      for (int fn = 0; fn < 4; ++fn)
        acc[fm][fn] = MFMA(af[fm], bfr[fn], acc[fm][fn], 0, 0, 0);
  }
#pragma unroll
  for (int fm = 0; fm < 4; ++fm)
#pragma unroll
    for (int fn = 0; fn < 4; ++fn) {
      const int m = mbase + wm * 64 + fm * 16 + q * 4;
      const int n = nbase + wn * 64 + fn * 16 + ln;
      f32x4 v = acc[fm][fn];
      bf16x4 o;
      o[0] = (__bf16)v[0]; o[1] = (__bf16)v[1];
      o[2] = (__bf16)v[2]; o[3] = (__bf16)v[3];
      *(bf16x4*)&Qw[(size_t)n * 256 + m] = o;
    }
}

// =====================================================================
// qwk: QWkb[bk][m'] = Qw @ Wk, K=256, grid 16
// =====================================================================
__global__ __launch_bounds__(256) void qwk(const __bf16* __restrict__ WkT,
                                           const __bf16* __restrict__ Qwp,
                                           __bf16* __restrict__ QWkb) {
  __shared__ __align__(16) __bf16 At[4096];
  __shared__ __align__(16) __bf16 Bt[4096];
  const int tid = threadIdx.x, lane = tid & 63;
  const int q = lane >> 4, ln = lane & 15;
  const int w = tid >> 6, wm = w >> 1, wn = w & 1;
  const int t = blockIdx.x;
  const int nbase = (t & 3) * 128;   // Qw rows (bk)
  const int mbase = (t >> 2) * 128;  // WkT rows (m')
  f32x4 acc[4][4] = {};
  for (int kt = 0; kt < 8; ++kt) {
    const int k0 = kt * 32;
    __syncthreads();
#pragma unroll
    for (int s = 0; s < 2; ++s) {
      const int cbase = (tid & 192) + s * 256;
      const int cc = cbase + lane;
      const int row = cc >> 2, kc = (cc & 3) * 8;
      cp16(&At[cbase * 8], WkT + (size_t)(mbase + row) * 256 + k0 + kc);
      cp16(&Bt[cbase * 8], Qwp + (size_t)(nbase + row) * 256 + k0 + kc);
    }
    __syncthreads();
    bf16x8 af[4], bfr[4];
#pragma unroll
    for (int f = 0; f < 4; ++f) {
      af[f]  = *(const bf16x8*)&At[(wm * 64 + f * 16 + ln) * 32 + q * 8];
      bfr[f] = *(const bf16x8*)&Bt[(wn * 64 + f * 16 + ln) * 32 + q * 8];
    }
#pragma unroll
    for (int fm = 0; fm < 4; ++fm)
#pragma unroll
      for (int fn = 0; fn < 4; ++fn)
        acc[fm][fn] = MFMA(af[fm], bfr[fn], acc[fm][fn], 0, 0, 0);
  }
#pragma unroll
  for (int fm = 0; fm < 4; ++fm)
#pragma unroll
    for (int fn = 0; fn < 4; ++fn) {
      const int m = mbase + wm * 64 + fm * 16 + q * 4;
      const int n = nbase + wn * 64 + fn * 16 + ln;
      f32x4 v = acc[fm][fn];
      bf16x4 o;
      o[0] = (__bf16)v[0]; o[1] = (__bf16)v[1];
      o[2] = (__bf16)v[2]; o[3] = (__bf16)v[3];
      *(bf16x4*)&QWkb[(size_t)n * 512 + m] = o;
    }
}

// =====================================================================
// fused_main v5: block = (c of 64 rows, b); 2 subtiles of 32 rows.
// 256 thr / 4 waves / ~44KB LDS -> 3 blocks/CU = 12 waves (the BW
// experiment). Er DELETED: GEMM1 B-frags = 8 consecutive m at fixed n
// = row-major global E, read directly (L2-hot: EtT staging fetched the
// same lines). LDS keeps only EtT (transposed, GEMM2's unavoidable
// col-access) + Plds. VMCNT0 staging discipline (always-safe).
// =====================================================================
__device__ __forceinline__ void load_e(f32x4 (&ev)[16], const float* Eb,
                                       int s, int rg, int cg0) {
#pragma unroll
  for (int i = 0; i < 4; ++i) {
    const int cg = cg0 + i * 32;
#pragma unroll
    for (int r = 0; r < 4; ++r)
      ev[i * 4 + r] = *(const f32x4*)(Eb + (size_t)(s * 32 + rg * 4 + r) * 512 + cg * 4);
  }
}
__device__ __forceinline__ void cvtwrite_t(const f32x4 (&ev)[16], char* EtT,
                                           int rg, int cg0) {
#pragma unroll
  for (int i = 0; i < 4; ++i) {
    const int cg = cg0 + i * 32;
#pragma unroll
    for (int j = 0; j < 4; ++j) {
      bf16x4 tw;                              // column j: n = rg*4..+3
      tw[0] = (__bf16)ev[i*4+0][j]; tw[1] = (__bf16)ev[i*4+1][j];
      tw[2] = (__bf16)ev[i*4+2][j]; tw[3] = (__bf16)ev[i*4+3][j];
      const int m = cg * 4 + j;
      const int u = (rg >> 1) ^ (m & 3);      // 16B-unit swizzle
      *(bf16x4*)(EtT + (size_t)m * 80 + u * 16 + (rg & 1) * 8) = tw;
    }
  }
}
__device__ __forceinline__ void phase1g(int s, const bf16x8 (&qf)[16],
                                        const float* Eb, __bf16* Plds,
                                        const float* Lp, float* rsum,
                                        int kf, int nf, int q, int ln) {
  const float* er = Eb + (size_t)(s * 32 + nf * 16 + ln) * 512 + q * 8;
  f32x4 sacc = {0.f, 0.f, 0.f, 0.f};
#pragma unroll
  for (int kk = 0; kk < 16; ++kk) {
    f32x4 e0 = *(const f32x4*)(er + kk * 32);
    f32x4 e1 = *(const f32x4*)(er + kk * 32 + 4);
    bf16x8 bb;
    bb[0] = (__bf16)e0[0]; bb[1] = (__bf16)e0[1];
    bb[2] = (__bf16)e0[2]; bb[3] = (__bf16)e0[3];
    bb[4] = (__bf16)e1[0]; bb[5] = (__bf16)e1[1];
    bb[6] = (__bf16)e1[2]; bb[7] = (__bf16)e1[3];
    sacc = MFMA(qf[kk], bb, sacc, 0, 0, 0);
  }
  const float lp = Lp[s * 32 + nf * 16 + ln];
  float pv[4];
#pragma unroll
  for (int r = 0; r < 4; ++r) {
    pv[r] = __expf(sacc[r] * 0.0625f + lp);
    *((__bf16*)((char*)Plds + (size_t)(kf * 16 + q * 4 + r) * 80) + nf * 16 + ln) = (__bf16)pv[r];
  }
#pragma unroll
  for (int mm = 1; mm < 16; mm <<= 1)
#pragma unroll
    for (int r = 0; r < 4; ++r) pv[r] += __shfl_xor(pv[r], mm, 64);
  if (ln == 0) {
#pragma unroll
    for (int r = 0; r < 4; ++r) atomicAdd(&rsum[kf * 16 + q * 4 + r], pv[r]);
  }
}
__device__ __forceinline__ void phase2(f32x4 (&facc)[2][8], const __bf16* Plds,
                                       const char* EtT, int w, int q, int ln,
                                       int tid, bf16x4* pr) {
  bf16x8 pa0 = *(const bf16x8*)((char*)Plds + (size_t)(ln) * 80 + q * 16);
  bf16x8 pa1 = *(const bf16x8*)((char*)Plds + (size_t)(16 + ln) * 80 + q * 16);
#pragma unroll
  for (int mf = 0; mf < 8; ++mf) {
    const int m = w * 128 + mf * 16 + ln;
    const int u = q ^ (m & 3);
    bf16x8 vb = *(const bf16x8*)(EtT + (size_t)m * 80 + u * 16);
    facc[0][mf] = MFMA(pa0, vb, facc[0][mf], 0, 0, 0);
    facc[1][mf] = MFMA(pa1, vb, facc[1][mf], 0, 0, 0);
  }
  *pr = *(const bf16x4*)((char*)Plds + (size_t)(tid >> 3) * 80 + (tid & 7) * 8);
}

__global__ __launch_bounds__(256, 3) void fused_main(
    const float* __restrict__ E, const __bf16* __restrict__ QWkb,
    const float* __restrict__ Pb, __bf16* __restrict__ Pws,
    float* __restrict__ Fpart, float* __restrict__ rowsum) {
  __shared__ __align__(16) char  EtT[512 * 80];     // 40960 B
  __shared__ __align__(16) __bf16 Plds[32 * 40];    //  2560 B
  __shared__ __align__(16) float Lp[64];
  __shared__ float rsum[32];

  const int tid = threadIdx.x;
  const int lane = tid & 63;
  const int q = lane >> 4, ln = lane & 15;
  const int w = tid >> 6;         // 0..3
  const int kf = w >> 1;          // GEMM1 k-frag (0..1)
  const int nf = w & 1;           // GEMM1 n-frag (0..1)
  const int b = blockIdx.y, c = blockIdx.x;   // c: 0..63, 64 rows each
  const int rg = tid >> 5;        // 0..7
  const int cg0 = tid & 31;

  const float* Eb = E + ((size_t)b * 4096 + (size_t)c * 64) * 512;

  // QWk A-fragments -> registers (reused both subtiles)
  bf16x8 qf[16];
  {
    const __bf16* qr = QWkb + (size_t)(b * 32 + kf * 16 + ln) * 512 + q * 8;
#pragma unroll
    for (int kk = 0; kk < 16; ++kk) qf[kk] = *(const bf16x8*)(qr + kk * 32);
  }
  if (tid < 64) {
    float p = Pb[b * 4096 + c * 64 + tid];
    Lp[tid] = __logf(fminf(fmaxf(p, 0.1f), 0.9f));
  }
  if (tid < 32) rsum[tid] = 0.f;

  f32x4 ev[16];
  load_e(ev, Eb, 0, rg, cg0);

  f32x4 facc[2][8] = {};
  bf16x4 pr0, pr1;

  // ---- s=0 ----
  VMCNT0;
  cvtwrite_t(ev, EtT, rg, cg0);
  load_e(ev, Eb, 1, rg, cg0);        // flies under phase1/2(0)
  LGKM0; BARRAW();
  phase1g(0, qf, Eb, Plds, Lp, rsum, kf, nf, q, ln);
  LGKM0; BARRAW();
  phase2(facc, Plds, EtT, w, q, ln, tid, &pr0);
  BARRAW();
  // ---- s=1 ----
  VMCNT0;
  cvtwrite_t(ev, EtT, rg, cg0);
  LGKM0; BARRAW();
  phase1g(1, qf, Eb, Plds, Lp, rsum, kf, nf, q, ln);
  LGKM0; BARRAW();
  phase2(facc, Plds, EtT, w, q, ln, tid, &pr1);

  // ---- epilogue: Pws (from regs), partial F plane, rowsum atomics ----
  {
    const int prow = tid >> 3, pc = (tid & 7) * 4;
    __bf16* pwr = Pws + (size_t)(b * 32 + prow) * 4096 + c * 64 + pc;
    *(bf16x4*)(pwr)      = pr0;
    *(bf16x4*)(pwr + 32) = pr1;
  }
  float* Fp = Fpart + ((size_t)c * 512 + b * 32) * 512;
#pragma unroll
  for (int kf2 = 0; kf2 < 2; ++kf2)
#pragma unroll
    for (int mf = 0; mf < 8; ++mf)
#pragma unroll
      for (int r = 0; r < 4; ++r)
        Fp[(size_t)(kf2 * 16 + q * 4 + r) * 512 + w * 128 + mf * 16 + ln] = facc[kf2][mf][r];
  if (tid < 32) atomicAdd(&rowsum[b * 32 + tid], rsum[tid]);
}

// =====================================================================
// norm_p: A(f32) = Pws(bf16) / rowsum[row]  (proven)
// =====================================================================
__global__ __launch_bounds__(256) void norm_p(const __bf16* __restrict__ Pws,
                                              const float* __restrict__ rowsum,
                                              float* __restrict__ Aout) {
  const size_t idx = ((size_t)blockIdx.x * 256 + threadIdx.x) * 4;
  const int row = (int)(idx >> 12);
  const float invs = 1.0f / rowsum[row];
  bf16x4 p = *(const bf16x4*)(Pws + idx);
  f32x4 o;
  o[0] = (float)p[0] * invs; o[1] = (float)p[1] * invs;
  o[2] = (float)p[2] * invs; o[3] = (float)p[3] * invs;
  *(f32x4*)(Aout + idx) = o;
}

// =====================================================================
// final_kernel v4: 2 rows/block (grid 256) -- halves L2 weight re-read
// vs r9's 1-row. Shuffle-free phases (r9-proven); 64 Fpart chunks.
// =====================================================================
__global__ __launch_bounds__(256) void final_kernel(const float* __restrict__ Fpart,
                                                    const float* __restrict__ WvT,
                                                    const float* __restrict__ WoT,
                                                    float* __restrict__ Fout) {
  __shared__ float fl[2][512];
  __shared__ float agg[2][256];
  __shared__ float f2b[2][512];
  __shared__ float redbuf[2][4];
  const int r0 = blockIdx.x * 2;
  const int t = threadIdx.x;
  const int lane = t & 63;
  const int w = t >> 6;

  // ---- phase 1: Fsum rows r0, r0+1 (chunk-reduce, coalesced) ----
#pragma unroll
  for (int r = 0; r < 2; ++r) {
    float s0 = 0.f, s1 = 0.f;
#pragma unroll
    for (int cc = 0; cc < 64; ++cc) {
      const float* p = Fpart + (size_t)cc * 262144 + (size_t)(r0 + r) * 512;
      s0 += p[t]; s1 += p[t + 256];
    }
    fl[r][t] = s0; fl[r][t + 256] = s1;
  }
  __syncthreads();

  // ---- phase 2: agg[r][t] = sum_m fl[r][m] * WvT[m][t] (coalesced) ----
  {
    float a00 = 0.f, a01 = 0.f, a02 = 0.f, a03 = 0.f;
    float a10 = 0.f, a11 = 0.f, a12 = 0.f, a13 = 0.f;
    for (int m = 0; m < 512; m += 4) {
      const float w0 = WvT[(size_t)(m + 0) * 256 + t];
      const float w1 = WvT[(size_t)(m + 1) * 256 + t];
      const float w2 = WvT[(size_t)(m + 2) * 256 + t];
      const float w3 = WvT[(size_t)(m + 3) * 256 + t];
      a00 += fl[0][m] * w0; a01 += fl[0][m + 1] * w1;
      a02 += fl[0][m + 2] * w2; a03 += fl[0][m + 3] * w3;
      a10 += fl[1][m] * w0; a11 += fl[1][m + 1] * w1;
      a12 += fl[1][m + 2] * w2; a13 += fl[1][m + 3] * w3;
    }
    agg[0][t] = (a00 + a01) + (a02 + a03);
    agg[1][t] = (a10 + a11) + (a12 + a13);
  }
  __syncthreads();

  // ---- phase 3: F2[r][t], F2[r][t+256] = sum_d agg[r][d]*WoT[d][.] ----
  {
    float b0 = 0.f, b1 = 0.f, c0 = 0.f, c1 = 0.f;
    float d0a = 0.f, d1a = 0.f, e0 = 0.f, e1 = 0.f;
    for (int d = 0; d < 256; d += 2) {
      const float g00 = agg[0][d], g01 = agg[0][d + 1];
      const float g10 = agg[1][d], g11 = agg[1][d + 1];
      const float w0 = WoT[(size_t)(d + 0) * 512 + t];
      const float w1 = WoT[(size_t)(d + 1) * 512 + t];
      const float x0 = WoT[(size_t)(d + 0) * 512 + t + 256];
      const float x1 = WoT[(size_t)(d + 1) * 512 + t + 256];
      b0 += g00 * w0; b1 += g01 * w1;    // row0, lo half
      c0 += g00 * x0; c1 += g01 * x1;    // row0, hi half
      d0a += g10 * w0; d1a += g11 * w1;  // row1, lo half
      e0 += g10 * x0; e1 += g11 * x1;    // row1, hi half
    }
    f2b[0][t] = b0 + b1;       f2b[0][t + 256] = c0 + c1;
    f2b[1][t] = d0a + d1a;     f2b[1][t + 256] = e0 + e1;
  }
  __syncthreads();

  // ---- phase 4: L2 norm + store ----
#pragma unroll
  for (int r = 0; r < 2; ++r) {
    const float x0 = f2b[r][t], x1 = f2b[r][t + 256];
    float ps = x0 * x0 + x1 * x1;
#pragma unroll
    for (int mm = 1; mm < 64; mm <<= 1) ps += __shfl_xor(ps, mm, 64);
    if (lane == 0) redbuf[r][w] = ps;
  }
  __syncthreads();
#pragma unroll
  for (int r = 0; r < 2; ++r) {
    const float tot = redbuf[r][0] + redbuf[r][1] + redbuf[r][2] + redbuf[r][3];
    const float sc = 1.0f / (sqrtf(tot) + 1e-8f);
    Fout[(size_t)(r0 + r) * 512 + t] = f2b[r][t] * sc;
    Fout[(size_t)(r0 + r) * 512 + t + 256] = f2b[r][t + 256] * sc;
  }
}

// =====================================================================
extern "C" void kernel_launch(void* const* d_in, const int* in_sizes, int n_in,
                              void* d_out, int out_size, void* d_ws, size_t ws_size,
                              hipStream_t stream) {
  const float* E  = (const float*)d_in[0];  // [16,4096,512]
  const float* T  = (const float*)d_in[1];  // [16,32,512]
  const float* Pb = (const float*)d_in[2];  // [16,4096]
  const float* Wq = (const float*)d_in[3];  // [256,512]
  const float* Wk = (const float*)d_in[4];
  const float* Wv = (const float*)d_in[5];
  const float* Wo = (const float*)d_in[6];  // [512,256]

  float* out  = (float*)d_out;
  float* Fout = out;             // [512][512] f32
  float* Aout = out + 262144;    // [512][4096] f32

  char* ws = (char*)d_ws;
  float*  Fpart = (float*)ws;                    // [64][512][512] f32  67108864 B
  __bf16* Pws   = (__bf16*)(ws + 67108864);      // [512][4096] bf16     4194304 B
  __bf16* Tbf   = (__bf16*)(ws + 71303168);      //                       524288 B
  __bf16* Wqb   = (__bf16*)(ws + 71827456);      //                       262144 B
  __bf16* WkT   = (__bf16*)(ws + 72089600);      // [512][256] bf16       262144 B
  float*  WvT   = (float*)(ws + 72351744);       // [512][256] f32        524288 B
  __bf16* Qw    = (__bf16*)(ws + 72876032);      // [512][256] bf16       262144 B
  __bf16* QWkb  = (__bf16*)(ws + 73138176);      // [512][512] bf16       524288 B
  float*  rowsum = (float*)(ws + 73662464);      // [512] f32 (2048 B)
  float*  WoT   = (float*)(ws + 73664512);       // [256][512] f32        524288 B

  hipMemsetAsync(rowsum, 0, 2048, stream);

  cvt_small<<<480, 256, 0, stream>>>(Wq, Wk, Wv, Wo, T, Wqb, Tbf, WkT, WvT, WoT);
  qproj<<<8, 256, 0, stream>>>(Wqb, Tbf, Qw);
  qwk<<<16, 256, 0, stream>>>(WkT, Qw, QWkb);
  fused_main<<<dim3(64, 16), 256, 0, stream>>>(E, QWkb, Pb, Pws, Fpart, rowsum);
  norm_p<<<2048, 256, 0, stream>>>(Pws, rowsum, Aout);
  final_kernel<<<256, 256, 0, stream>>>(Fpart, WvT, WoT, Fout);
}

// Round 12
// 276.991 us; speedup vs baseline: 1.2867x; 1.2867x over previous
//
#include <hip/hip_runtime.h>

// ---------- types ----------
typedef __bf16 bf16x8 __attribute__((ext_vector_type(8)));
typedef __bf16 bf16x4 __attribute__((ext_vector_type(4)));
typedef float  f32x4  __attribute__((ext_vector_type(4)));

// async global->LDS, 16B per lane; LDS dest = wave-uniform base + lane*16
__device__ __forceinline__ void cp16(void* lds, const void* g) {
  __builtin_amdgcn_global_load_lds(
      (const __attribute__((address_space(1))) unsigned int*)g,
      (__attribute__((address_space(3))) unsigned int*)lds, 16, 0, 0);
}

#define VMCNT0  asm volatile("s_waitcnt vmcnt(0)" ::: "memory")
#define LGKM0   asm volatile("s_waitcnt lgkmcnt(0)" ::: "memory")
#define BARRAW  __builtin_amdgcn_s_barrier
#define MFMA    __builtin_amdgcn_mfma_f32_16x16x32_bf16

// =====================================================================
// ALGORITHM (r5 restructure): K/V never materialized.
//   scores = (Q@Wk) . E ; F_unnorm = P @ E (fused, E read once)
//   Fout = L2norm((F_unnorm@Wv^T)@Wo^T)  (rowsum cancels in L2 norm)
// r12: r11 reverted (direct-global GEMM1 reads were a scatter: FETCH
// 84->137MB, MfmaUtil 1.5%). fused_main v6 = r10's verified tile math
// (Er row-layout + EtT swizzled col-layout + VMCNT0 staging) at 512
// threads / 128 rows / 4 subtiles -> 81.5KB LDS, 2 blocks/CU x 8 waves
// = 16 waves/CU (r10 had 8). GEMM1 K-split across wave pairs with a
// 4KB f32 Sred reduce. This is the CLEAN wave-TLP test: identical
// access patterns, 2x waves. All other kernels = r10 exact.
// Fixed harness cost in dur: ~155us of 512MiB poison-fills.
// =====================================================================

// =====================================================================
// cvt_small: Wq->Wqb bf16, T->Tbf bf16, Wk->WkT bf16 [512m][256d],
//            Wv->WvT f32 [512m][256d], Wo->WoT f32 [256d][512m]
// =====================================================================
__global__ __launch_bounds__(256) void cvt_small(const float* __restrict__ Wq,
                                                 const float* __restrict__ Wk,
                                                 const float* __restrict__ Wv,
                                                 const float* __restrict__ Wo,
                                                 const float* __restrict__ T,
                                                 __bf16* __restrict__ Wqb,
                                                 __bf16* __restrict__ Tbf,
                                                 __bf16* __restrict__ WkT,
                                                 float* __restrict__ WvT,
                                                 float* __restrict__ WoT) {
  const int idx = blockIdx.x * 256 + threadIdx.x;
  if (idx < 32768) {
    const int o = idx * 4;
    f32x4 v = *(const f32x4*)(Wq + o);
    bf16x4 b;
    b[0] = (__bf16)v[0]; b[1] = (__bf16)v[1];
    b[2] = (__bf16)v[2]; b[3] = (__bf16)v[3];
    *(bf16x4*)(Wqb + o) = b;
  } else if (idx < 98304) {
    const int o = (idx - 32768) * 4;
    f32x4 v = *(const f32x4*)(T + o);
    bf16x4 b;
    b[0] = (__bf16)v[0]; b[1] = (__bf16)v[1];
    b[2] = (__bf16)v[2]; b[3] = (__bf16)v[3];
    *(bf16x4*)(Tbf + o) = b;
  } else if (idx < 106496) {
    const int t2 = idx - 98304;                 // Wk [256 d][512 m] -> WkT
    const int d0 = (t2 >> 7) * 4, m0 = (t2 & 127) * 4;
    f32x4 r0 = *(const f32x4*)(Wk + (size_t)(d0 + 0) * 512 + m0);
    f32x4 r1 = *(const f32x4*)(Wk + (size_t)(d0 + 1) * 512 + m0);
    f32x4 r2 = *(const f32x4*)(Wk + (size_t)(d0 + 2) * 512 + m0);
    f32x4 r3 = *(const f32x4*)(Wk + (size_t)(d0 + 3) * 512 + m0);
#pragma unroll
    for (int j = 0; j < 4; ++j) {
      bf16x4 o;
      o[0] = (__bf16)r0[j]; o[1] = (__bf16)r1[j];
      o[2] = (__bf16)r2[j]; o[3] = (__bf16)r3[j];
      *(bf16x4*)(WkT + (size_t)(m0 + j) * 256 + d0) = o;
    }
  } else if (idx < 114688) {
    const int t2 = idx - 106496;                // Wv [256 d][512 m] -> WvT f32
    const int d0 = (t2 >> 7) * 4, m0 = (t2 & 127) * 4;
    f32x4 r0 = *(const f32x4*)(Wv + (size_t)(d0 + 0) * 512 + m0);
    f32x4 r1 = *(const f32x4*)(Wv + (size_t)(d0 + 1) * 512 + m0);
    f32x4 r2 = *(const f32x4*)(Wv + (size_t)(d0 + 2) * 512 + m0);
    f32x4 r3 = *(const f32x4*)(Wv + (size_t)(d0 + 3) * 512 + m0);
#pragma unroll
    for (int j = 0; j < 4; ++j) {
      f32x4 o;
      o[0] = r0[j]; o[1] = r1[j]; o[2] = r2[j]; o[3] = r3[j];
      *(f32x4*)(WvT + (size_t)(m0 + j) * 256 + d0) = o;
    }
  } else {
    const int t2 = idx - 114688;                // Wo [512 m][256 d] -> WoT f32
    const int m0 = (t2 >> 6) * 4, d0 = (t2 & 63) * 4;
    f32x4 r0 = *(const f32x4*)(Wo + (size_t)(m0 + 0) * 256 + d0);
    f32x4 r1 = *(const f32x4*)(Wo + (size_t)(m0 + 1) * 256 + d0);
    f32x4 r2 = *(const f32x4*)(Wo + (size_t)(m0 + 2) * 256 + d0);
    f32x4 r3 = *(const f32x4*)(Wo + (size_t)(m0 + 3) * 256 + d0);
#pragma unroll
    for (int j = 0; j < 4; ++j) {
      f32x4 o;
      o[0] = r0[j]; o[1] = r1[j]; o[2] = r2[j]; o[3] = r3[j];
      *(f32x4*)(WoT + (size_t)(d0 + j) * 512 + m0) = o;
    }
  }
}

// =====================================================================
// qproj: Qw[bk][d] = T@Wq^T (verbatim proven m97 path, grid 8)
// =====================================================================
__global__ __launch_bounds__(256) void qproj(const __bf16* __restrict__ Wqb,
                                             const __bf16* __restrict__ Tbf,
                                             __bf16* __restrict__ Qw) {
  __shared__ __align__(16) __bf16 At[4096];
  __shared__ __align__(16) __bf16 Bt[4096];
  const int tid = threadIdx.x, lane = tid & 63;
  const int q = lane >> 4, ln = lane & 15;
  const int w = tid >> 6, wm = w >> 1, wn = w & 1;
  const int t = blockIdx.x;
  const int nbase = (t & 3) * 128;   // T rows (bk)
  const int mbase = (t >> 2) * 128;  // Wq rows (d)
  f32x4 acc[4][4] = {};
  for (int kt = 0; kt < 16; ++kt) {
    const int k0 = kt * 32;
    __syncthreads();
#pragma unroll
    for (int s = 0; s < 2; ++s) {
      const int cbase = (tid & 192) + s * 256;
      const int cc = cbase + lane;
      const int row = cc >> 2, kc = (cc & 3) * 8;
      cp16(&At[cbase * 8], Wqb + (size_t)(mbase + row) * 512 + k0 + kc);
      cp16(&Bt[cbase * 8], Tbf + (size_t)(nbase + row) * 512 + k0 + kc);
    }
    __syncthreads();
    bf16x8 af[4], bfr[4];
#pragma unroll
    for (int f = 0; f < 4; ++f) {
      af[f]  = *(const bf16x8*)&At[(wm * 64 + f * 16 + ln) * 32 + q * 8];
      bfr[f] = *(const bf16x8*)&Bt[(wn * 64 + f * 16 + ln) * 32 + q * 8];
    }
#pragma unroll
    for (int fm = 0; fm < 4; ++fm)
#pragma unroll
      for (int fn = 0; fn < 4; ++fn)
        acc[fm][fn] = MFMA(af[fm], bfr[fn], acc[fm][fn], 0, 0, 0);
  }
#pragma unroll
  for (int fm = 0; fm < 4; ++fm)
#pragma unroll
    for (int fn = 0; fn < 4; ++fn) {
      const int m = mbase + wm * 64 + fm * 16 + q * 4;
      const int n = nbase + wn * 64 + fn * 16 + ln;
      f32x4 v = acc[fm][fn];
      bf16x4 o;
      o[0] = (__bf16)v[0]; o[1] = (__bf16)v[1];
      o[2] = (__bf16)v[2]; o[3] = (__bf16)v[3];
      *(bf16x4*)&Qw[(size_t)n * 256 + m] = o;
    }
}

// =====================================================================
// qwk: QWkb[bk][m'] = Qw @ Wk, K=256, grid 16
// =====================================================================
__global__ __launch_bounds__(256) void qwk(const __bf16* __restrict__ WkT,
                                           const __bf16* __restrict__ Qwp,
                                           __bf16* __restrict__ QWkb) {
  __shared__ __align__(16) __bf16 At[4096];
  __shared__ __align__(16) __bf16 Bt[4096];
  const int tid = threadIdx.x, lane = tid & 63;
  const int q = lane >> 4, ln = lane & 15;
  const int w = tid >> 6, wm = w >> 1, wn = w & 1;
  const int t = blockIdx.x;
  const int nbase = (t & 3) * 128;   // Qw rows (bk)
  const int mbase = (t >> 2) * 128;  // WkT rows (m')
  f32x4 acc[4][4] = {};
  for (int kt = 0; kt < 8; ++kt) {
    const int k0 = kt * 32;
    __syncthreads();
#pragma unroll
    for (int s = 0; s < 2; ++s) {
      const int cbase = (tid & 192) + s * 256;
      const int cc = cbase + lane;
      const int row = cc >> 2, kc = (cc & 3) * 8;
      cp16(&At[cbase * 8], WkT + (size_t)(mbase + row) * 256 + k0 + kc);
      cp16(&Bt[cbase * 8], Qwp + (size_t)(nbase + row) * 256 + k0 + kc);
    }
    __syncthreads();
    bf16x8 af[4], bfr[4];
#pragma unroll
    for (int f = 0; f < 4; ++f) {
      af[f]  = *(const bf16x8*)&At[(wm * 64 + f * 16 + ln) * 32 + q * 8];
      bfr[f] = *(const bf16x8*)&Bt[(wn * 64 + f * 16 + ln) * 32 + q * 8];
    }
#pragma unroll
    for (int fm = 0; fm < 4; ++fm)
#pragma unroll
      for (int fn = 0; fn < 4; ++fn)
        acc[fm][fn] = MFMA(af[fm], bfr[fn], acc[fm][fn], 0, 0, 0);
  }
#pragma unroll
  for (int fm = 0; fm < 4; ++fm)
#pragma unroll
    for (int fn = 0; fn < 4; ++fn) {
      const int m = mbase + wm * 64 + fm * 16 + q * 4;
      const int n = nbase + wn * 64 + fn * 16 + ln;
      f32x4 v = acc[fm][fn];
      bf16x4 o;
      o[0] = (__bf16)v[0]; o[1] = (__bf16)v[1];
      o[2] = (__bf16)v[2]; o[3] = (__bf16)v[3];
      *(bf16x4*)&QWkb[(size_t)n * 512 + m] = o;
    }
}

// =====================================================================
// fused_main v6: block = (c of 128 rows, b); 4 subtiles of 32 rows.
// 512 thr / 8 waves / 81.5KB LDS -> 2 blocks/CU = 16 WAVES/CU (the
// clean TLP test; r10 = same patterns at 8 waves/CU). Per subtile:
// VMCNT0 commit; issue load(s+1); barrier; GEMM1 K-SPLIT (kh=0/1 wave
// pairs, f32 partials reduced via Sred) + P; barrier; GEMM2 (8 waves x
// 64 m); Pws copy; barrier. Er/EtT/Plds layouts byte-identical to r10.
// =====================================================================
__device__ __forceinline__ void load_e6(f32x4 (&ev)[8], const float* Eb,
                                        int s, int rg, int cg0) {
#pragma unroll
  for (int i = 0; i < 2; ++i) {
    const int cg = cg0 + i * 64;
#pragma unroll
    for (int r = 0; r < 4; ++r)
      ev[i * 4 + r] = *(const f32x4*)(Eb + (size_t)(s * 32 + rg * 4 + r) * 512 + cg * 4);
  }
}
__device__ __forceinline__ void cvtwrite6(const f32x4 (&ev)[8], char* Er,
                                          char* EtT, int rg, int cg0) {
#pragma unroll
  for (int i = 0; i < 2; ++i) {
    const int cg = cg0 + i * 64;
#pragma unroll
    for (int r = 0; r < 4; ++r) {
      bf16x4 rw;
      rw[0] = (__bf16)ev[i*4+r][0]; rw[1] = (__bf16)ev[i*4+r][1];
      rw[2] = (__bf16)ev[i*4+r][2]; rw[3] = (__bf16)ev[i*4+r][3];
      *(bf16x4*)(Er + (size_t)(rg * 4 + r) * 1040 + cg * 8) = rw;
    }
#pragma unroll
    for (int j = 0; j < 4; ++j) {
      bf16x4 tw;                              // column j: n = rg*4..+3
      tw[0] = (__bf16)ev[i*4+0][j]; tw[1] = (__bf16)ev[i*4+1][j];
      tw[2] = (__bf16)ev[i*4+2][j]; tw[3] = (__bf16)ev[i*4+3][j];
      const int m = cg * 4 + j;
      const int u = (rg >> 1) ^ (m & 3);      // 16B-unit swizzle (r10)
      *(bf16x4*)(EtT + (size_t)m * 80 + u * 16 + (rg & 1) * 8) = tw;
    }
  }
}

__global__ __launch_bounds__(512, 4) void fused_main(
    const float* __restrict__ E, const __bf16* __restrict__ QWkb,
    const float* __restrict__ Pb, __bf16* __restrict__ Pws,
    float* __restrict__ Fpart, float* __restrict__ rowsum) {
  __shared__ __align__(16) char Er[32 * 1040];      // 33280 B
  __shared__ __align__(16) char EtT[512 * 80];      // 40960 B
  __shared__ __align__(16) char Plds[32 * 80];      //  2560 B
  __shared__ __align__(16) float Sred[32 * 32];     //  4096 B
  __shared__ float Lp[128];
  __shared__ float rsum[32];

  const int tid = threadIdx.x;
  const int lane = tid & 63;
  const int q = lane >> 4, ln = lane & 15;
  const int w = tid >> 6;         // 0..7
  const int kf = (w >> 1) & 1;    // GEMM1 k-frag
  const int nf = w & 1;           // GEMM1 n-frag
  const int kh = w >> 2;          // GEMM1 K-half (0: kk 0..7, 1: kk 8..15)
  const int b = blockIdx.y, c = blockIdx.x;   // c: 0..31, 128 rows each
  const int rg = tid >> 6;        // == w, rows rg*4..+3
  const int cg0 = tid & 63;

  const float* Eb = E + ((size_t)b * 4096 + (size_t)c * 128) * 512;

  // QWk A-fragments for this wave's K-half (8 frags = 32 VGPR)
  bf16x8 qf[8];
  {
    const __bf16* qr = QWkb + (size_t)(b * 32 + kf * 16 + ln) * 512 + kh * 256 + q * 8;
#pragma unroll
    for (int kkl = 0; kkl < 8; ++kkl) qf[kkl] = *(const bf16x8*)(qr + kkl * 32);
  }
  if (tid < 128) {
    float p = Pb[b * 4096 + c * 128 + tid];
    Lp[tid] = __logf(fminf(fmaxf(p, 0.1f), 0.9f));
  }
  if (tid < 32) rsum[tid] = 0.f;

  f32x4 ev[8];
  load_e6(ev, Eb, 0, rg, cg0);
  f32x4 facc[2][4] = {};

#pragma unroll
  for (int s = 0; s < 4; ++s) {
    // ---- stage commit + next-load issue ----
    VMCNT0;
    cvtwrite6(ev, Er, EtT, rg, cg0);
    if (s < 3) load_e6(ev, Eb, s + 1, rg, cg0);   // flies under compute(s)
    LGKM0; BARRAW();

    // ---- phase1: GEMM1 K-split + P ----
    {
      f32x4 sacc = {0.f, 0.f, 0.f, 0.f};
#pragma unroll
      for (int kkl = 0; kkl < 8; ++kkl) {
        const int kk = kh * 8 + kkl;
        bf16x8 bb = *(const bf16x8*)(Er + (size_t)(nf * 16 + ln) * 1040 + kk * 64 + q * 16);
        sacc = MFMA(qf[kkl], bb, sacc, 0, 0, 0);
      }
      if (kh) {
#pragma unroll
        for (int r = 0; r < 4; ++r)
          Sred[(kf * 16 + q * 4 + r) * 32 + nf * 16 + ln] = sacc[r];
      }
      LGKM0; BARRAW();
      if (!kh) {
        const float lp = Lp[s * 32 + nf * 16 + ln];
        float pv[4];
#pragma unroll
        for (int r = 0; r < 4; ++r) {
          const float sv = sacc[r] + Sred[(kf * 16 + q * 4 + r) * 32 + nf * 16 + ln];
          pv[r] = __expf(sv * 0.0625f + lp);
          *((__bf16*)(Plds + (size_t)(kf * 16 + q * 4 + r) * 80) + nf * 16 + ln) = (__bf16)pv[r];
        }
#pragma unroll
        for (int mm = 1; mm < 16; mm <<= 1)
#pragma unroll
          for (int r = 0; r < 4; ++r) pv[r] += __shfl_xor(pv[r], mm, 64);
        if (ln == 0) {
#pragma unroll
          for (int r = 0; r < 4; ++r) atomicAdd(&rsum[kf * 16 + q * 4 + r], pv[r]);
        }
      }
      LGKM0; BARRAW();
    }

    // ---- phase2: GEMM2, 8 waves x 64 m ----
    {
      bf16x8 pa0 = *(const bf16x8*)(Plds + (size_t)(ln) * 80 + q * 16);
      bf16x8 pa1 = *(const bf16x8*)(Plds + (size_t)(16 + ln) * 80 + q * 16);
#pragma unroll
      for (int mf = 0; mf < 4; ++mf) {
        const int m = w * 64 + mf * 16 + ln;
        const int u = q ^ (m & 3);
        bf16x8 vb = *(const bf16x8*)(EtT + (size_t)m * 80 + u * 16);
        facc[0][mf] = MFMA(pa0, vb, facc[0][mf], 0, 0, 0);
        facc[1][mf] = MFMA(pa1, vb, facc[1][mf], 0, 0, 0);
      }
    }
    // ---- Pws copy (Plds still valid) ----
    if (tid < 256) {
      bf16x4 pc4 = *(const bf16x4*)(Plds + (size_t)(tid >> 3) * 80 + (tid & 7) * 8);
      *(bf16x4*)(Pws + (size_t)(b * 32 + (tid >> 3)) * 4096 + c * 128 + s * 32 + (tid & 7) * 4) = pc4;
    }
    if (s < 3) BARRAW();          // protect Er/EtT/Plds before next commit
  }

  // ---- epilogue: partial F plane + rowsum atomics ----
  float* Fp = Fpart + ((size_t)c * 512 + b * 32) * 512;
#pragma unroll
  for (int kf2 = 0; kf2 < 2; ++kf2)
#pragma unroll
    for (int mf = 0; mf < 4; ++mf)
#pragma unroll
      for (int r = 0; r < 4; ++r)
        Fp[(size_t)(kf2 * 16 + q * 4 + r) * 512 + w * 64 + mf * 16 + ln] = facc[kf2][mf][r];
  if (tid < 32) atomicAdd(&rowsum[b * 32 + tid], rsum[tid]);
}

// =====================================================================
// norm_p: A(f32) = Pws(bf16) / rowsum[row]  (proven)
// =====================================================================
__global__ __launch_bounds__(256) void norm_p(const __bf16* __restrict__ Pws,
                                              const float* __restrict__ rowsum,
                                              float* __restrict__ Aout) {
  const size_t idx = ((size_t)blockIdx.x * 256 + threadIdx.x) * 4;
  const int row = (int)(idx >> 12);
  const float invs = 1.0f / rowsum[row];
  bf16x4 p = *(const bf16x4*)(Pws + idx);
  f32x4 o;
  o[0] = (float)p[0] * invs; o[1] = (float)p[1] * invs;
  o[2] = (float)p[2] * invs; o[3] = (float)p[3] * invs;
  *(f32x4*)(Aout + idx) = o;
}

// =====================================================================
// final_kernel v3 (r10-verified): 1 row/block, grid 512, 32 chunks.
// Shuffle-free coalesced phases via WvT/WoT.
// =====================================================================
__global__ __launch_bounds__(256) void final_kernel(const float* __restrict__ Fpart,
                                                    const float* __restrict__ WvT,
                                                    const float* __restrict__ WoT,
                                                    float* __restrict__ Fout) {
  __shared__ float fl[512];
  __shared__ float agg[256];
  __shared__ float f2b[512];
  __shared__ float redbuf[4];
  const int row = blockIdx.x;
  const int t = threadIdx.x;
  const int lane = t & 63;
  const int w = t >> 6;

  // ---- phase 1: Fsum row (chunk-reduce, coalesced) ----
  {
    float s0 = 0.f, s1 = 0.f;
#pragma unroll
    for (int cc = 0; cc < 32; ++cc) {
      const float* p = Fpart + (size_t)cc * 262144 + (size_t)row * 512;
      s0 += p[t]; s1 += p[t + 256];
    }
    fl[t] = s0; fl[t + 256] = s1;
  }
  __syncthreads();

  // ---- phase 2: agg[t] = sum_m fl[m] * WvT[m][t] (coalesced) ----
  {
    float a0 = 0.f, a1 = 0.f, a2 = 0.f, a3 = 0.f;
    for (int m = 0; m < 512; m += 4) {
      a0 += fl[m]     * WvT[(size_t)(m + 0) * 256 + t];
      a1 += fl[m + 1] * WvT[(size_t)(m + 1) * 256 + t];
      a2 += fl[m + 2] * WvT[(size_t)(m + 2) * 256 + t];
      a3 += fl[m + 3] * WvT[(size_t)(m + 3) * 256 + t];
    }
    agg[t] = (a0 + a1) + (a2 + a3);
  }
  __syncthreads();

  // ---- phase 3: F2[t], F2[t+256] = sum_d agg[d] * WoT[d][.] ----
  {
    float b0 = 0.f, b1 = 0.f, b2 = 0.f, b3 = 0.f;
    float c0 = 0.f, c1 = 0.f, c2 = 0.f, c3 = 0.f;
    for (int d = 0; d < 256; d += 4) {
      const float g0 = agg[d], g1 = agg[d + 1], g2 = agg[d + 2], g3 = agg[d + 3];
      b0 += g0 * WoT[(size_t)(d + 0) * 512 + t];
      b1 += g1 * WoT[(size_t)(d + 1) * 512 + t];
      b2 += g2 * WoT[(size_t)(d + 2) * 512 + t];
      b3 += g3 * WoT[(size_t)(d + 3) * 512 + t];
      c0 += g0 * WoT[(size_t)(d + 0) * 512 + t + 256];
      c1 += g1 * WoT[(size_t)(d + 1) * 512 + t + 256];
      c2 += g2 * WoT[(size_t)(d + 2) * 512 + t + 256];
      c3 += g3 * WoT[(size_t)(d + 3) * 512 + t + 256];
    }
    f2b[t] = (b0 + b1) + (b2 + b3);
    f2b[t + 256] = (c0 + c1) + (c2 + c3);
  }
  __syncthreads();

  // ---- phase 4: L2 norm + store ----
  {
    const float x0 = f2b[t], x1 = f2b[t + 256];
    float ps = x0 * x0 + x1 * x1;
#pragma unroll
    for (int mm = 1; mm < 64; mm <<= 1) ps += __shfl_xor(ps, mm, 64);
    if (lane == 0) redbuf[w] = ps;
  }
  __syncthreads();
  {
    const float tot = redbuf[0] + redbuf[1] + redbuf[2] + redbuf[3];
    const float sc = 1.0f / (sqrtf(tot) + 1e-8f);
    Fout[(size_t)row * 512 + t] = f2b[t] * sc;
    Fout[(size_t)row * 512 + t + 256] = f2b[t + 256] * sc;
  }
}

// =====================================================================
extern "C" void kernel_launch(void* const* d_in, const int* in_sizes, int n_in,
                              void* d_out, int out_size, void* d_ws, size_t ws_size,
                              hipStream_t stream) {
  const float* E  = (const float*)d_in[0];  // [16,4096,512]
  const float* T  = (const float*)d_in[1];  // [16,32,512]
  const float* Pb = (const float*)d_in[2];  // [16,4096]
  const float* Wq = (const float*)d_in[3];  // [256,512]
  const float* Wk = (const float*)d_in[4];
  const float* Wv = (const float*)d_in[5];
  const float* Wo = (const float*)d_in[6];  // [512,256]

  float* out  = (float*)d_out;
  float* Fout = out;             // [512][512] f32
  float* Aout = out + 262144;    // [512][4096] f32

  char* ws = (char*)d_ws;
  float*  Fpart = (float*)ws;                    // [32][512][512] f32  33554432 B
  __bf16* Pws   = (__bf16*)(ws + 33554432);      // [512][4096] bf16     4194304 B
  __bf16* Tbf   = (__bf16*)(ws + 37748736);      //                       524288 B
  __bf16* Wqb   = (__bf16*)(ws + 38273024);      //                       262144 B
  __bf16* WkT   = (__bf16*)(ws + 38535168);      // [512][256] bf16       262144 B
  float*  WvT   = (float*)(ws + 38797312);       // [512][256] f32        524288 B
  __bf16* Qw    = (__bf16*)(ws + 39321600);      // [512][256] bf16       262144 B
  __bf16* QWkb  = (__bf16*)(ws + 39583744);      // [512][512] bf16       524288 B
  float*  rowsum = (float*)(ws + 40108032);      // [512] f32 (2048 B)
  float*  WoT   = (float*)(ws + 40110080);       // [256][512] f32        524288 B

  hipMemsetAsync(rowsum, 0, 2048, stream);

  cvt_small<<<480, 256, 0, stream>>>(Wq, Wk, Wv, Wo, T, Wqb, Tbf, WkT, WvT, WoT);
  qproj<<<8, 256, 0, stream>>>(Wqb, Tbf, Qw);
  qwk<<<16, 256, 0, stream>>>(WkT, Qw, QWkb);
  fused_main<<<dim3(32, 16), 512, 0, stream>>>(E, QWkb, Pb, Pws, Fpart, rowsum);
  norm_p<<<2048, 256, 0, stream>>>(Pws, rowsum, Aout);
  final_kernel<<<512, 256, 0, stream>>>(Fpart, WvT, WoT, Fout);
}

// Round 13
// 268.087 us; speedup vs baseline: 1.3294x; 1.0332x over previous
//
#include <hip/hip_runtime.h>

// ---------- types ----------
typedef __bf16 bf16x8 __attribute__((ext_vector_type(8)));
typedef __bf16 bf16x4 __attribute__((ext_vector_type(4)));
typedef float  f32x4  __attribute__((ext_vector_type(4)));

// async global->LDS, 16B per lane; LDS dest = wave-uniform base + lane*16
__device__ __forceinline__ void cp16(void* lds, const void* g) {
  __builtin_amdgcn_global_load_lds(
      (const __attribute__((address_space(1))) unsigned int*)g,
      (__attribute__((address_space(3))) unsigned int*)lds, 16, 0, 0);
}

#define VMCNT0  asm volatile("s_waitcnt vmcnt(0)" ::: "memory")
#define LGKM0   asm volatile("s_waitcnt lgkmcnt(0)" ::: "memory")
#define BARRAW  __builtin_amdgcn_s_barrier
#define MFMA    __builtin_amdgcn_mfma_f32_16x16x32_bf16

// =====================================================================
// ALGORITHM (r5 restructure): K/V never materialized.
//   scores = (Q@Wk) . E ; F_unnorm = P @ E (fused, E read once)
//   Fout = L2norm((F_unnorm@Wv^T)@Wo^T)  (rowsum cancels in L2 norm)
// r13: CONSOLIDATION to the best-measured configuration (r10, 268us).
// r12's clean wave-TLP test was NULL (occupancy 18->41%, BW unchanged
// at 1.9 TB/s) -- the per-CU delivery rate of the barriered
// stage->transpose->MFMA structure is invariant under schedule,
// occupancy, swizzle, and tile changes (8 falsified levers, r2-r12).
// This is the r10 kernel set verbatim.
// =====================================================================

// =====================================================================
// cvt_small: Wq->Wqb bf16, T->Tbf bf16, Wk->WkT bf16 [512m][256d],
//            Wv->WvT f32 [512m][256d], Wo->WoT f32 [256d][512m]
// =====================================================================
__global__ __launch_bounds__(256) void cvt_small(const float* __restrict__ Wq,
                                                 const float* __restrict__ Wk,
                                                 const float* __restrict__ Wv,
                                                 const float* __restrict__ Wo,
                                                 const float* __restrict__ T,
                                                 __bf16* __restrict__ Wqb,
                                                 __bf16* __restrict__ Tbf,
                                                 __bf16* __restrict__ WkT,
                                                 float* __restrict__ WvT,
                                                 float* __restrict__ WoT) {
  const int idx = blockIdx.x * 256 + threadIdx.x;
  if (idx < 32768) {
    const int o = idx * 4;
    f32x4 v = *(const f32x4*)(Wq + o);
    bf16x4 b;
    b[0] = (__bf16)v[0]; b[1] = (__bf16)v[1];
    b[2] = (__bf16)v[2]; b[3] = (__bf16)v[3];
    *(bf16x4*)(Wqb + o) = b;
  } else if (idx < 98304) {
    const int o = (idx - 32768) * 4;
    f32x4 v = *(const f32x4*)(T + o);
    bf16x4 b;
    b[0] = (__bf16)v[0]; b[1] = (__bf16)v[1];
    b[2] = (__bf16)v[2]; b[3] = (__bf16)v[3];
    *(bf16x4*)(Tbf + o) = b;
  } else if (idx < 106496) {
    const int t2 = idx - 98304;                 // Wk [256 d][512 m] -> WkT
    const int d0 = (t2 >> 7) * 4, m0 = (t2 & 127) * 4;
    f32x4 r0 = *(const f32x4*)(Wk + (size_t)(d0 + 0) * 512 + m0);
    f32x4 r1 = *(const f32x4*)(Wk + (size_t)(d0 + 1) * 512 + m0);
    f32x4 r2 = *(const f32x4*)(Wk + (size_t)(d0 + 2) * 512 + m0);
    f32x4 r3 = *(const f32x4*)(Wk + (size_t)(d0 + 3) * 512 + m0);
#pragma unroll
    for (int j = 0; j < 4; ++j) {
      bf16x4 o;
      o[0] = (__bf16)r0[j]; o[1] = (__bf16)r1[j];
      o[2] = (__bf16)r2[j]; o[3] = (__bf16)r3[j];
      *(bf16x4*)(WkT + (size_t)(m0 + j) * 256 + d0) = o;
    }
  } else if (idx < 114688) {
    const int t2 = idx - 106496;                // Wv [256 d][512 m] -> WvT f32
    const int d0 = (t2 >> 7) * 4, m0 = (t2 & 127) * 4;
    f32x4 r0 = *(const f32x4*)(Wv + (size_t)(d0 + 0) * 512 + m0);
    f32x4 r1 = *(const f32x4*)(Wv + (size_t)(d0 + 1) * 512 + m0);
    f32x4 r2 = *(const f32x4*)(Wv + (size_t)(d0 + 2) * 512 + m0);
    f32x4 r3 = *(const f32x4*)(Wv + (size_t)(d0 + 3) * 512 + m0);
#pragma unroll
    for (int j = 0; j < 4; ++j) {
      f32x4 o;
      o[0] = r0[j]; o[1] = r1[j]; o[2] = r2[j]; o[3] = r3[j];
      *(f32x4*)(WvT + (size_t)(m0 + j) * 256 + d0) = o;
    }
  } else {
    const int t2 = idx - 114688;                // Wo [512 m][256 d] -> WoT f32
    const int m0 = (t2 >> 6) * 4, d0 = (t2 & 63) * 4;
    f32x4 r0 = *(const f32x4*)(Wo + (size_t)(m0 + 0) * 256 + d0);
    f32x4 r1 = *(const f32x4*)(Wo + (size_t)(m0 + 1) * 256 + d0);
    f32x4 r2 = *(const f32x4*)(Wo + (size_t)(m0 + 2) * 256 + d0);
    f32x4 r3 = *(const f32x4*)(Wo + (size_t)(m0 + 3) * 256 + d0);
#pragma unroll
    for (int j = 0; j < 4; ++j) {
      f32x4 o;
      o[0] = r0[j]; o[1] = r1[j]; o[2] = r2[j]; o[3] = r3[j];
      *(f32x4*)(WoT + (size_t)(d0 + j) * 512 + m0) = o;
    }
  }
}

// =====================================================================
// qproj: Qw[bk][d] = T@Wq^T (verbatim proven m97 path, grid 8)
// =====================================================================
__global__ __launch_bounds__(256) void qproj(const __bf16* __restrict__ Wqb,
                                             const __bf16* __restrict__ Tbf,
                                             __bf16* __restrict__ Qw) {
  __shared__ __align__(16) __bf16 At[4096];
  __shared__ __align__(16) __bf16 Bt[4096];
  const int tid = threadIdx.x, lane = tid & 63;
  const int q = lane >> 4, ln = lane & 15;
  const int w = tid >> 6, wm = w >> 1, wn = w & 1;
  const int t = blockIdx.x;
  const int nbase = (t & 3) * 128;   // T rows (bk)
  const int mbase = (t >> 2) * 128;  // Wq rows (d)
  f32x4 acc[4][4] = {};
  for (int kt = 0; kt < 16; ++kt) {
    const int k0 = kt * 32;
    __syncthreads();
#pragma unroll
    for (int s = 0; s < 2; ++s) {
      const int cbase = (tid & 192) + s * 256;
      const int cc = cbase + lane;
      const int row = cc >> 2, kc = (cc & 3) * 8;
      cp16(&At[cbase * 8], Wqb + (size_t)(mbase + row) * 512 + k0 + kc);
      cp16(&Bt[cbase * 8], Tbf + (size_t)(nbase + row) * 512 + k0 + kc);
    }
    __syncthreads();
    bf16x8 af[4], bfr[4];
#pragma unroll
    for (int f = 0; f < 4; ++f) {
      af[f]  = *(const bf16x8*)&At[(wm * 64 + f * 16 + ln) * 32 + q * 8];
      bfr[f] = *(const bf16x8*)&Bt[(wn * 64 + f * 16 + ln) * 32 + q * 8];
    }
#pragma unroll
    for (int fm = 0; fm < 4; ++fm)
#pragma unroll
      for (int fn = 0; fn < 4; ++fn)
        acc[fm][fn] = MFMA(af[fm], bfr[fn], acc[fm][fn], 0, 0, 0);
  }
#pragma unroll
  for (int fm = 0; fm < 4; ++fm)
#pragma unroll
    for (int fn = 0; fn < 4; ++fn) {
      const int m = mbase + wm * 64 + fm * 16 + q * 4;
      const int n = nbase + wn * 64 + fn * 16 + ln;
      f32x4 v = acc[fm][fn];
      bf16x4 o;
      o[0] = (__bf16)v[0]; o[1] = (__bf16)v[1];
      o[2] = (__bf16)v[2]; o[3] = (__bf16)v[3];
      *(bf16x4*)&Qw[(size_t)n * 256 + m] = o;
    }
}

// =====================================================================
// qwk: QWkb[bk][m'] = Qw @ Wk, K=256, grid 16
// =====================================================================
__global__ __launch_bounds__(256) void qwk(const __bf16* __restrict__ WkT,
                                           const __bf16* __restrict__ Qwp,
                                           __bf16* __restrict__ QWkb) {
  __shared__ __align__(16) __bf16 At[4096];
  __shared__ __align__(16) __bf16 Bt[4096];
  const int tid = threadIdx.x, lane = tid & 63;
  const int q = lane >> 4, ln = lane & 15;
  const int w = tid >> 6, wm = w >> 1, wn = w & 1;
  const int t = blockIdx.x;
  const int nbase = (t & 3) * 128;   // Qw rows (bk)
  const int mbase = (t >> 2) * 128;  // WkT rows (m')
  f32x4 acc[4][4] = {};
  for (int kt = 0; kt < 8; ++kt) {
    const int k0 = kt * 32;
    __syncthreads();
#pragma unroll
    for (int s = 0; s < 2; ++s) {
      const int cbase = (tid & 192) + s * 256;
      const int cc = cbase + lane;
      const int row = cc >> 2, kc = (cc & 3) * 8;
      cp16(&At[cbase * 8], WkT + (size_t)(mbase + row) * 256 + k0 + kc);
      cp16(&Bt[cbase * 8], Qwp + (size_t)(nbase + row) * 256 + k0 + kc);
    }
    __syncthreads();
    bf16x8 af[4], bfr[4];
#pragma unroll
    for (int f = 0; f < 4; ++f) {
      af[f]  = *(const bf16x8*)&At[(wm * 64 + f * 16 + ln) * 32 + q * 8];
      bfr[f] = *(const bf16x8*)&Bt[(wn * 64 + f * 16 + ln) * 32 + q * 8];
    }
#pragma unroll
    for (int fm = 0; fm < 4; ++fm)
#pragma unroll
      for (int fn = 0; fn < 4; ++fn)
        acc[fm][fn] = MFMA(af[fm], bfr[fn], acc[fm][fn], 0, 0, 0);
  }
#pragma unroll
  for (int fm = 0; fm < 4; ++fm)
#pragma unroll
    for (int fn = 0; fn < 4; ++fn) {
      const int m = mbase + wm * 64 + fm * 16 + q * 4;
      const int n = nbase + wn * 64 + fn * 16 + ln;
      f32x4 v = acc[fm][fn];
      bf16x4 o;
      o[0] = (__bf16)v[0]; o[1] = (__bf16)v[1];
      o[2] = (__bf16)v[2]; o[3] = (__bf16)v[3];
      *(bf16x4*)&QWkb[(size_t)n * 512 + m] = o;
    }
}

// =====================================================================
// fused_main v4 (r10-verified, best measured): per block (c=chunk of
// 128 rows, b): 4 subtiles of 32. 256 thr / 4 waves / ~77KB LDS ->
// 2 blocks/CU. Per subtile: VMCNT0; commit ev->Er+EtT; issue
// load(s+1); bar; GEMM1+P; bar; GEMM2; bar.
// =====================================================================
__device__ __forceinline__ void load_e(f32x4 (&ev)[16], const float* Eb,
                                       int s, int rg, int cg0) {
#pragma unroll
  for (int i = 0; i < 4; ++i) {
    const int cg = cg0 + i * 32;
#pragma unroll
    for (int r = 0; r < 4; ++r)
      ev[i * 4 + r] = *(const f32x4*)(Eb + (size_t)(s * 32 + rg * 4 + r) * 512 + cg * 4);
  }
}
__device__ __forceinline__ void cvtwrite_e(const f32x4 (&ev)[16], __bf16* Er,
                                           char* EtT, int rg, int cg0) {
#pragma unroll
  for (int i = 0; i < 4; ++i) {
    const int cg = cg0 + i * 32;
#pragma unroll
    for (int r = 0; r < 4; ++r) {
      bf16x4 rw;
      rw[0] = (__bf16)ev[i*4+r][0]; rw[1] = (__bf16)ev[i*4+r][1];
      rw[2] = (__bf16)ev[i*4+r][2]; rw[3] = (__bf16)ev[i*4+r][3];
      *(bf16x4*)((char*)Er + (size_t)(rg * 4 + r) * 1040 + cg * 8) = rw;
    }
#pragma unroll
    for (int j = 0; j < 4; ++j) {
      bf16x4 tw;                              // column j: n = rg*4..+3
      tw[0] = (__bf16)ev[i*4+0][j]; tw[1] = (__bf16)ev[i*4+1][j];
      tw[2] = (__bf16)ev[i*4+2][j]; tw[3] = (__bf16)ev[i*4+3][j];
      const int m = cg * 4 + j;
      const int u = (rg >> 1) ^ (m & 3);      // 16B-unit swizzle
      *(bf16x4*)(EtT + (size_t)m * 80 + u * 16 + (rg & 1) * 8) = tw;
    }
  }
}
__device__ __forceinline__ void phase1(int s, const bf16x8 (&qf)[16],
                                       const __bf16* Er, __bf16* Plds,
                                       const float* Lp, float* rsum,
                                       int kf, int nf, int q, int ln) {
  f32x4 sacc = {0.f, 0.f, 0.f, 0.f};
#pragma unroll
  for (int kk = 0; kk < 16; ++kk) {
    bf16x8 bb = *(const bf16x8*)((char*)Er + (size_t)(nf * 16 + ln) * 1040 + kk * 64 + q * 16);
    sacc = MFMA(qf[kk], bb, sacc, 0, 0, 0);
  }
  const float lp = Lp[s * 32 + nf * 16 + ln];
  float pv[4];
#pragma unroll
  for (int r = 0; r < 4; ++r) {
    pv[r] = __expf(sacc[r] * 0.0625f + lp);
    *((__bf16*)((char*)Plds + (size_t)(kf * 16 + q * 4 + r) * 80) + nf * 16 + ln) = (__bf16)pv[r];
  }
#pragma unroll
  for (int mm = 1; mm < 16; mm <<= 1)
#pragma unroll
    for (int r = 0; r < 4; ++r) pv[r] += __shfl_xor(pv[r], mm, 64);
  if (ln == 0) {
#pragma unroll
    for (int r = 0; r < 4; ++r) atomicAdd(&rsum[kf * 16 + q * 4 + r], pv[r]);
  }
}
__device__ __forceinline__ void phase2(f32x4 (&facc)[2][8], const __bf16* Plds,
                                       const char* EtT, int w, int q, int ln,
                                       int tid, bf16x4* pr) {
  bf16x8 pa0 = *(const bf16x8*)((char*)Plds + (size_t)(ln) * 80 + q * 16);
  bf16x8 pa1 = *(const bf16x8*)((char*)Plds + (size_t)(16 + ln) * 80 + q * 16);
#pragma unroll
  for (int mf = 0; mf < 8; ++mf) {
    const int m = w * 128 + mf * 16 + ln;
    const int u = q ^ (m & 3);
    bf16x8 vb = *(const bf16x8*)(EtT + (size_t)m * 80 + u * 16);
    facc[0][mf] = MFMA(pa0, vb, facc[0][mf], 0, 0, 0);
    facc[1][mf] = MFMA(pa1, vb, facc[1][mf], 0, 0, 0);
  }
  *pr = *(const bf16x4*)((char*)Plds + (size_t)(tid >> 3) * 80 + (tid & 7) * 8);
}

__global__ __launch_bounds__(256, 2) void fused_main(
    const float* __restrict__ E, const __bf16* __restrict__ QWkb,
    const float* __restrict__ Pb, __bf16* __restrict__ Pws,
    float* __restrict__ Fpart, float* __restrict__ rowsum) {
  __shared__ __align__(16) __bf16 Er[32 * 520];     // 33280 B
  __shared__ __align__(16) char  EtT[512 * 80];     // 40960 B
  __shared__ __align__(16) __bf16 Plds[32 * 40];    //  2560 B
  __shared__ __align__(16) float Lp[128];
  __shared__ float rsum[32];

  const int tid = threadIdx.x;
  const int lane = tid & 63;
  const int q = lane >> 4, ln = lane & 15;
  const int w = tid >> 6;         // 0..3
  const int kf = w >> 1;          // GEMM1 k-frag (0..1)
  const int nf = w & 1;           // GEMM1 n-frag (0..1)
  const int b = blockIdx.y, c = blockIdx.x;   // c: 0..31, 128 rows each
  const int rg = tid >> 5;        // 0..7
  const int cg0 = tid & 31;

  const float* Eb = E + ((size_t)b * 4096 + (size_t)c * 128) * 512;

  // QWk A-fragments -> registers (64 VGPR, reused all subtiles)
  bf16x8 qf[16];
  {
    const __bf16* qr = QWkb + (size_t)(b * 32 + kf * 16 + ln) * 512 + q * 8;
#pragma unroll
    for (int kk = 0; kk < 16; ++kk) qf[kk] = *(const bf16x8*)(qr + kk * 32);
  }
  if (tid < 128) {
    float p = Pb[b * 4096 + c * 128 + tid];
    Lp[tid] = __logf(fminf(fmaxf(p, 0.1f), 0.9f));
  }
  if (tid < 32) rsum[tid] = 0.f;

  f32x4 ev[16];
  load_e(ev, Eb, 0, rg, cg0);

  f32x4 facc[2][8] = {};
  bf16x4 pr0, pr1, pr2, pr3;

  // ---- s=0 ----
  VMCNT0;
  cvtwrite_e(ev, Er, EtT, rg, cg0);
  load_e(ev, Eb, 1, rg, cg0);        // flies under phase1/2(0)
  LGKM0; BARRAW();
  phase1(0, qf, Er, Plds, Lp, rsum, kf, nf, q, ln);
  LGKM0; BARRAW();
  phase2(facc, Plds, EtT, w, q, ln, tid, &pr0);
  BARRAW();
  // ---- s=1 ----
  VMCNT0;
  cvtwrite_e(ev, Er, EtT, rg, cg0);
  load_e(ev, Eb, 2, rg, cg0);
  LGKM0; BARRAW();
  phase1(1, qf, Er, Plds, Lp, rsum, kf, nf, q, ln);
  LGKM0; BARRAW();
  phase2(facc, Plds, EtT, w, q, ln, tid, &pr1);
  BARRAW();
  // ---- s=2 ----
  VMCNT0;
  cvtwrite_e(ev, Er, EtT, rg, cg0);
  load_e(ev, Eb, 3, rg, cg0);
  LGKM0; BARRAW();
  phase1(2, qf, Er, Plds, Lp, rsum, kf, nf, q, ln);
  LGKM0; BARRAW();
  phase2(facc, Plds, EtT, w, q, ln, tid, &pr2);
  BARRAW();
  // ---- s=3 ----
  VMCNT0;
  cvtwrite_e(ev, Er, EtT, rg, cg0);
  LGKM0; BARRAW();
  phase1(3, qf, Er, Plds, Lp, rsum, kf, nf, q, ln);
  LGKM0; BARRAW();
  phase2(facc, Plds, EtT, w, q, ln, tid, &pr3);

  // ---- epilogue: Pws (from regs), partial F plane, rowsum atomics ----
  {
    const int prow = tid >> 3, pc = (tid & 7) * 4;
    __bf16* pwr = Pws + (size_t)(b * 32 + prow) * 4096 + c * 128 + pc;
    *(bf16x4*)(pwr)      = pr0;
    *(bf16x4*)(pwr + 32) = pr1;
    *(bf16x4*)(pwr + 64) = pr2;
    *(bf16x4*)(pwr + 96) = pr3;
  }
  float* Fp = Fpart + ((size_t)c * 512 + b * 32) * 512;
#pragma unroll
  for (int kf2 = 0; kf2 < 2; ++kf2)
#pragma unroll
    for (int mf = 0; mf < 8; ++mf)
#pragma unroll
      for (int r = 0; r < 4; ++r)
        Fp[(size_t)(kf2 * 16 + q * 4 + r) * 512 + w * 128 + mf * 16 + ln] = facc[kf2][mf][r];
  if (tid < 32) atomicAdd(&rowsum[b * 32 + tid], rsum[tid]);
}

// =====================================================================
// norm_p: A(f32) = Pws(bf16) / rowsum[row]  (proven)
// =====================================================================
__global__ __launch_bounds__(256) void norm_p(const __bf16* __restrict__ Pws,
                                              const float* __restrict__ rowsum,
                                              float* __restrict__ Aout) {
  const size_t idx = ((size_t)blockIdx.x * 256 + threadIdx.x) * 4;
  const int row = (int)(idx >> 12);
  const float invs = 1.0f / rowsum[row];
  bf16x4 p = *(const bf16x4*)(Pws + idx);
  f32x4 o;
  o[0] = (float)p[0] * invs; o[1] = (float)p[1] * invs;
  o[2] = (float)p[2] * invs; o[3] = (float)p[3] * invs;
  *(f32x4*)(Aout + idx) = o;
}

// =====================================================================
// final_kernel v3 (r9/r10-verified): 1 row/block, grid 512, 32 chunks.
// Shuffle-free coalesced phases via WvT/WoT.
// =====================================================================
__global__ __launch_bounds__(256) void final_kernel(const float* __restrict__ Fpart,
                                                    const float* __restrict__ WvT,
                                                    const float* __restrict__ WoT,
                                                    float* __restrict__ Fout) {
  __shared__ float fl[512];
  __shared__ float agg[256];
  __shared__ float f2b[512];
  __shared__ float redbuf[4];
  const int row = blockIdx.x;
  const int t = threadIdx.x;
  const int lane = t & 63;
  const int w = t >> 6;

  // ---- phase 1: Fsum row (chunk-reduce, coalesced) ----
  {
    float s0 = 0.f, s1 = 0.f;
#pragma unroll
    for (int cc = 0; cc < 32; ++cc) {
      const float* p = Fpart + (size_t)cc * 262144 + (size_t)row * 512;
      s0 += p[t]; s1 += p[t + 256];
    }
    fl[t] = s0; fl[t + 256] = s1;
  }
  __syncthreads();

  // ---- phase 2: agg[t] = sum_m fl[m] * WvT[m][t] (coalesced) ----
  {
    float a0 = 0.f, a1 = 0.f, a2 = 0.f, a3 = 0.f;
    for (int m = 0; m < 512; m += 4) {
      a0 += fl[m]     * WvT[(size_t)(m + 0) * 256 + t];
      a1 += fl[m + 1] * WvT[(size_t)(m + 1) * 256 + t];
      a2 += fl[m + 2] * WvT[(size_t)(m + 2) * 256 + t];
      a3 += fl[m + 3] * WvT[(size_t)(m + 3) * 256 + t];
    }
    agg[t] = (a0 + a1) + (a2 + a3);
  }
  __syncthreads();

  // ---- phase 3: F2[t], F2[t+256] = sum_d agg[d] * WoT[d][.] ----
  {
    float b0 = 0.f, b1 = 0.f, b2 = 0.f, b3 = 0.f;
    float c0 = 0.f, c1 = 0.f, c2 = 0.f, c3 = 0.f;
    for (int d = 0; d < 256; d += 4) {
      const float g0 = agg[d], g1 = agg[d + 1], g2 = agg[d + 2], g3 = agg[d + 3];
      b0 += g0 * WoT[(size_t)(d + 0) * 512 + t];
      b1 += g1 * WoT[(size_t)(d + 1) * 512 + t];
      b2 += g2 * WoT[(size_t)(d + 2) * 512 + t];
      b3 += g3 * WoT[(size_t)(d + 3) * 512 + t];
      c0 += g0 * WoT[(size_t)(d + 0) * 512 + t + 256];
      c1 += g1 * WoT[(size_t)(d + 1) * 512 + t + 256];
      c2 += g2 * WoT[(size_t)(d + 2) * 512 + t + 256];
      c3 += g3 * WoT[(size_t)(d + 3) * 512 + t + 256];
    }
    f2b[t] = (b0 + b1) + (b2 + b3);
    f2b[t + 256] = (c0 + c1) + (c2 + c3);
  }
  __syncthreads();

  // ---- phase 4: L2 norm + store ----
  {
    const float x0 = f2b[t], x1 = f2b[t + 256];
    float ps = x0 * x0 + x1 * x1;
#pragma unroll
    for (int mm = 1; mm < 64; mm <<= 1) ps += __shfl_xor(ps, mm, 64);
    if (lane == 0) redbuf[w] = ps;
  }
  __syncthreads();
  {
    const float tot = redbuf[0] + redbuf[1] + redbuf[2] + redbuf[3];
    const float sc = 1.0f / (sqrtf(tot) + 1e-8f);
    Fout[(size_t)row * 512 + t] = f2b[t] * sc;
    Fout[(size_t)row * 512 + t + 256] = f2b[t + 256] * sc;
  }
}

// =====================================================================
extern "C" void kernel_launch(void* const* d_in, const int* in_sizes, int n_in,
                              void* d_out, int out_size, void* d_ws, size_t ws_size,
                              hipStream_t stream) {
  const float* E  = (const float*)d_in[0];  // [16,4096,512]
  const float* T  = (const float*)d_in[1];  // [16,32,512]
  const float* Pb = (const float*)d_in[2];  // [16,4096]
  const float* Wq = (const float*)d_in[3];  // [256,512]
  const float* Wk = (const float*)d_in[4];
  const float* Wv = (const float*)d_in[5];
  const float* Wo = (const float*)d_in[6];  // [512,256]

  float* out  = (float*)d_out;
  float* Fout = out;             // [512][512] f32
  float* Aout = out + 262144;    // [512][4096] f32

  char* ws = (char*)d_ws;
  float*  Fpart = (float*)ws;                    // [32][512][512] f32  33554432 B
  __bf16* Pws   = (__bf16*)(ws + 33554432);      // [512][4096] bf16     4194304 B
  __bf16* Tbf   = (__bf16*)(ws + 37748736);      //                       524288 B
  __bf16* Wqb   = (__bf16*)(ws + 38273024);      //                       262144 B
  __bf16* WkT   = (__bf16*)(ws + 38535168);      // [512][256] bf16       262144 B
  float*  WvT   = (float*)(ws + 38797312);       // [512][256] f32        524288 B
  __bf16* Qw    = (__bf16*)(ws + 39321600);      // [512][256] bf16       262144 B
  __bf16* QWkb  = (__bf16*)(ws + 39583744);      // [512][512] bf16       524288 B
  float*  rowsum = (float*)(ws + 40108032);      // [512] f32 (2048 B)
  float*  WoT   = (float*)(ws + 40110080);       // [256][512] f32        524288 B

  hipMemsetAsync(rowsum, 0, 2048, stream);

  cvt_small<<<480, 256, 0, stream>>>(Wq, Wk, Wv, Wo, T, Wqb, Tbf, WkT, WvT, WoT);
  qproj<<<8, 256, 0, stream>>>(Wqb, Tbf, Qw);
  qwk<<<16, 256, 0, stream>>>(WkT, Qw, QWkb);
  fused_main<<<dim3(32, 16), 256, 0, stream>>>(E, QWkb, Pb, Pws, Fpart, rowsum);
  norm_p<<<2048, 256, 0, stream>>>(Pws, rowsum, Aout);
  final_kernel<<<512, 256, 0, stream>>>(Fpart, WvT, WoT, Fout);
}